// Round 5
// baseline (2451.586 us; speedup 1.0000x reference)
//
#include <hip/hip_runtime.h>
#include <cstddef>
#include <cstdint>

#define TPB 256

typedef unsigned int u32;
typedef unsigned short u16;
typedef __bf16 bf16x8 __attribute__((ext_vector_type(8)));
typedef float f32x4 __attribute__((ext_vector_type(4)));

template<int ACT>
__device__ __forceinline__ float act_f(float v) {
  if (ACT == 1) return v >= 0.f ? v : 0.1f * v;          // lrelu
  if (ACT == 2) return 1.f / (1.f + expf(-v));           // sigmoid
  return v;
}

__device__ __forceinline__ u16 f2bf(float f) {           // fp32 -> bf16 RNE
  u32 u = __float_as_uint(f);
  u32 r = u + 0x7FFFu + ((u >> 16) & 1u);
  return (u16)(r >> 16);
}
__device__ __forceinline__ float bf2f(u16 h) {
  return __uint_as_float(((u32)h) << 16);
}

// ---------------------------------------------------------------------------
// Weight prep (single launch for all 22 convs): fp32 [Cout][Cin][3][3] ->
// bf16 hi/lo planes as [kc][tap][plane][co(pad)][40].  blockIdx.y = segment.
// ---------------------------------------------------------------------------
struct WPrepArgs {
  const float* src[22];
  u16* dst[22];
  int cin[22], cout[22], coutpad[22], total[22];
};

__global__ void k_wprep_all(WPrepArgs a)
{
  const int seg = blockIdx.y;
  const int idx = blockIdx.x * TPB + threadIdx.x;
  if (idx >= a.total[seg]) return;
  const int Cin = a.cin[seg], Cout = a.cout[seg], Coutpad = a.coutpad[seg];
  int kk = idx % 40; int t = idx / 40;
  int co = t % Coutpad; t /= Coutpad;
  int plane = t & 1; t >>= 1;
  int tap = t % 9; int kc = t / 9;
  u16 v = 0;
  if (kk < 32 && co < Cout) {
    float w0 = a.src[seg][((size_t)co * Cin + kc * 32 + kk) * 9 + tap];
    u16 hi = f2bf(w0);
    v = plane ? f2bf(w0 - bf2f(hi)) : hi;
  }
  a.dst[seg][idx] = v;
}

// ---------------------------------------------------------------------------
// 3x3 conv via MFMA bf16 3-pass split (unchanged from round 2).
// ---------------------------------------------------------------------------
template<int ACT>
__global__ __launch_bounds__(TPB, 2)
void k_conv_mfma(const float* __restrict__ in1, int c1,
                 const float* __restrict__ in2, int c2,
                 const u16* __restrict__ wbuf, const float* __restrict__ bias,
                 float* __restrict__ out, int Cout, int Coutpad, int Hh, int Ww)
{
  __shared__ __align__(16) u16 s_act[18 * 18 * 72];
  __shared__ __align__(16) u16 s_w[3 * 2 * 64 * 40];
  const int Cin = c1 + c2;
  const int b   = blockIdx.z;
  const int cb  = blockIdx.y << 6;
  const int xt  = Ww >> 4;
  const int by0 = (blockIdx.x / xt) << 4;
  const int bx0 = (blockIdx.x % xt) << 4;
  const int tid = threadIdx.x;
  const int lx = tid & 15, slot = (tid >> 4) & 3, wv = tid >> 6;
  const int HW = Hh * Ww;

  f32x4 acc[4][4];
#pragma unroll
  for (int i = 0; i < 4; ++i)
#pragma unroll
    for (int j = 0; j < 4; ++j) acc[i][j] = (f32x4){0.f, 0.f, 0.f, 0.f};

#pragma unroll 1
  for (int kc = 0; kc < (Cin >> 5); ++kc) {
    __syncthreads();
    // ---- stage activations: 18x18 positions x 32 ci, fp32 -> bf16 hi/lo ----
    {
      const int cbase = kc << 5;
      const float* sp = (cbase < c1) ? in1 + ((size_t)b * c1 + cbase) * HW
                                     : in2 + ((size_t)b * c2 + (cbase - c1)) * HW;
#pragma unroll 1
      for (int u = tid; u < 324; u += TPB) {
        int y = u / 18, x = u - y * 18;
        int gy = by0 - 1 + y, gx = bx0 - 1 + x;
        bool inb = ((unsigned)gy < (unsigned)Hh) & ((unsigned)gx < (unsigned)Ww);
        const float msk = inb ? 1.f : 0.f;
        const size_t poff = inb ? ((size_t)gy * Ww + gx) : 0;
        const float* s0 = sp + poff;
        u16* dp = &s_act[(y * 18 + x) * 72];
#pragma unroll
        for (int c8 = 0; c8 < 4; ++c8) {
          u32 hb[4], lb[4];
#pragma unroll
          for (int j = 0; j < 4; ++j) {
            float a0 = s0[(size_t)(c8 * 8 + 2 * j) * HW] * msk;
            float a1 = s0[(size_t)(c8 * 8 + 2 * j + 1) * HW] * msk;
            u16 h0 = f2bf(a0), h1 = f2bf(a1);
            hb[j] = (u32)h0 | ((u32)h1 << 16);
            lb[j] = (u32)f2bf(a0 - bf2f(h0)) | ((u32)f2bf(a1 - bf2f(h1)) << 16);
          }
          *(uint4*)&dp[c8 * 8]      = make_uint4(hb[0], hb[1], hb[2], hb[3]);
          *(uint4*)&dp[32 + c8 * 8] = make_uint4(lb[0], lb[1], lb[2], lb[3]);
        }
      }
    }
#pragma unroll 1
    for (int ky = 0; ky < 3; ++ky) {
      __syncthreads();
      {
        const size_t segstride = (size_t)Coutpad * 40;
        const size_t tb = (size_t)((kc * 9 + ky * 3) * 2) * segstride + (size_t)cb * 40;
#pragma unroll 1
        for (int i = tid; i < 1920; i += TPB) {
          int seg = i / 320, j = i - seg * 320;
          const uint4 v = *(const uint4*)&wbuf[tb + (size_t)seg * segstride + j * 8];
          *(uint4*)&s_w[seg * 2560 + j * 8] = v;
        }
      }
      __syncthreads();
#pragma unroll
      for (int kx = 0; kx < 3; ++kx) {
        bf16x8 Af[4][2], Bf[4][2];
#pragma unroll
        for (int ct = 0; ct < 4; ++ct)
#pragma unroll
          for (int p = 0; p < 2; ++p)
            Af[ct][p] = *(const bf16x8*)&s_w[((kx * 2 + p) * 64 + ct * 16 + lx) * 40 + slot * 8];
#pragma unroll
        for (int pg = 0; pg < 4; ++pg)
#pragma unroll
          for (int p = 0; p < 2; ++p)
            Bf[pg][p] = *(const bf16x8*)&s_act[((wv * 4 + pg + ky) * 18 + lx + kx) * 72 + p * 32 + slot * 8];
#pragma unroll
        for (int ct = 0; ct < 4; ++ct)
#pragma unroll
          for (int pg = 0; pg < 4; ++pg) {
            acc[ct][pg] = __builtin_amdgcn_mfma_f32_16x16x32_bf16(Af[ct][0], Bf[pg][0], acc[ct][pg], 0, 0, 0);
            acc[ct][pg] = __builtin_amdgcn_mfma_f32_16x16x32_bf16(Af[ct][1], Bf[pg][0], acc[ct][pg], 0, 0, 0);
            acc[ct][pg] = __builtin_amdgcn_mfma_f32_16x16x32_bf16(Af[ct][0], Bf[pg][1], acc[ct][pg], 0, 0, 0);
          }
      }
    }
  }
  const int ox = bx0 + lx;
#pragma unroll
  for (int ct = 0; ct < 4; ++ct) {
    const int co0 = cb + ct * 16 + slot * 4;
#pragma unroll
    for (int r = 0; r < 4; ++r) {
      const int co = co0 + r;
      if (co < Cout) {
        const float bv = bias[co];
        float* op = out + ((size_t)b * Cout + co) * HW + (size_t)(by0 + wv * 4) * Ww + ox;
#pragma unroll
        for (int pg = 0; pg < 4; ++pg)
          op[pg * Ww] = act_f<ACT>(acc[ct][pg][r] + bv);
      }
    }
  }
}

// ---------------------------------------------------------------------------
// Modulated deformable 3x3 conv, v4: 16x16 tile (64B-coalesced om reads and
// out writes), 4 groups per block via blockIdx.y (gsplit) -> LDS 35KB,
// 4 blocks/CU. Tap loop FULLY UNROLLED, om reads inline (no runtime-indexed
// arrays -> no scratch). Out-of-window samples fall back to clamped global.
// ---------------------------------------------------------------------------
template<int SIGM, int ACT>
__global__ __launch_bounds__(TPB, 4)
void k_dconv4(const float* __restrict__ x,
              const float* __restrict__ off,
              const float* __restrict__ mask, int maskC, int maskBase,
              const float* __restrict__ wgt, const float* __restrict__ bias,
              float* __restrict__ out, int Hh, int Ww)
{
  __shared__ __align__(16) u16 s_x[32][400];        // 4 groups x 8ch, 20x20 halo
  __shared__ __align__(16) float s_w[4 * 9 * 64];   // [gl][k][c][o]
  __shared__ float s_b[32];
  const int b   = blockIdx.z;
  const int gs  = blockIdx.y;                       // group half: gs*4..gs*4+3
  const int xt  = Ww >> 4;
  const int ty0 = (blockIdx.x / xt) << 4;
  const int tx0 = (blockIdx.x % xt) << 4;
  const int tid = threadIdx.x;
  const int HW  = Hh * Ww;
  const int cb  = gs * 32;

  for (int i = tid; i < 2304; i += TPB) {
    int o = i & 7, c = (i >> 3) & 7, k = (i >> 6) % 9, gl = i / 576;
    s_w[i] = wgt[(((size_t)((gs * 4 + gl) * 8 + o)) * 8 + c) * 9 + k];
  }
  if (tid < 32) s_b[tid] = bias[cb + tid];
  const float* xb = x + ((size_t)b * 64 + cb) * HW;
  for (int i = tid; i < 32 * 400; i += TPB) {
    int c = i / 400, rem = i - c * 400;
    int r = rem / 20, cx = rem - r * 20;
    int gy = ty0 - 2 + r, gx = tx0 - 2 + cx;
    float v = 0.f;
    if ((unsigned)gy < (unsigned)Hh && (unsigned)gx < (unsigned)Ww)
      v = xb[(size_t)c * HW + gy * Ww + gx];
    s_x[c][rem] = f2bf(v);
  }
  __syncthreads();

  const int py_ = tid >> 4, px_ = tid & 15;
  const int gy = ty0 + py_, gx = tx0 + px_;
  const int p  = gy * Ww + gx;

#pragma unroll 1
  for (int gl = 0; gl < 4; ++gl) {
    const int g = gs * 4 + gl;
    const float* ob = off  + ((size_t)b * 216 + g * 18) * HW + p;
    const float* mb = mask + ((size_t)b * maskC + maskBase + g * 9) * HW + p;
    const float* xg = x    + ((size_t)b * 64 + g * 8) * HW;
    float*       og = out  + ((size_t)b * 64 + g * 8) * HW + p;
    const float* wg = &s_w[gl * 9 * 64];

    float acc[8];
#pragma unroll
    for (int o = 0; o < 8; ++o) acc[o] = s_b[gl * 8 + o];

#pragma unroll
    for (int k = 0; k < 9; ++k) {
      const float oyk = ob[(size_t)(2 * k) * HW];
      const float oxk = ob[(size_t)(2 * k + 1) * HW];
      float m = mb[(size_t)k * HW];
      if (SIGM) m = 1.f / (1.f + expf(-m));
      const float py = (float)(gy + k / 3 - 1) + oyk;
      const float px = (float)(gx + k % 3 - 1) + oxk;
      const float y0f = floorf(py), x0f = floorf(px);
      const float fy = py - y0f, fx = px - x0f;
      const int y0 = (int)y0f, x0 = (int)x0f;
      const int y1 = y0 + 1, x1 = x0 + 1;
      const float vy0 = (y0 >= 0 && y0 < Hh) ? 1.f : 0.f;
      const float vy1 = (y1 >= 0 && y1 < Hh) ? 1.f : 0.f;
      const float vx0 = (x0 >= 0 && x0 < Ww) ? 1.f : 0.f;
      const float vx1 = (x1 >= 0 && x1 < Ww) ? 1.f : 0.f;
      const float w00 = (1.f - fy) * (1.f - fx) * vy0 * vx0 * m;
      const float w01 = (1.f - fy) * fx * vy0 * vx1 * m;
      const float w10 = fy * (1.f - fx) * vy1 * vx0 * m;
      const float w11 = fy * fx * vy1 * vx1 * m;
      const float* wk = &wg[k * 64];
      const int ly = y0 - ty0 + 2, lxw = x0 - tx0 + 2;
      if ((unsigned)ly < 19u && (unsigned)lxw < 19u) {
        const int base = ly * 20 + lxw;
#pragma unroll
        for (int c = 0; c < 8; ++c) {
          const u16* pc = &s_x[gl * 8 + c][0];
          const float s = w00 * bf2f(pc[base])      + w01 * bf2f(pc[base + 1])
                        + w10 * bf2f(pc[base + 20]) + w11 * bf2f(pc[base + 21]);
          const float4 wv0 = *(const float4*)&wk[c * 8];
          const float4 wv1 = *(const float4*)&wk[c * 8 + 4];
          acc[0] = fmaf(s, wv0.x, acc[0]); acc[1] = fmaf(s, wv0.y, acc[1]);
          acc[2] = fmaf(s, wv0.z, acc[2]); acc[3] = fmaf(s, wv0.w, acc[3]);
          acc[4] = fmaf(s, wv1.x, acc[4]); acc[5] = fmaf(s, wv1.y, acc[5]);
          acc[6] = fmaf(s, wv1.z, acc[6]); acc[7] = fmaf(s, wv1.w, acc[7]);
        }
      } else {
        const int cy0 = min(max(y0, 0), Hh - 1), cy1 = min(max(y1, 0), Hh - 1);
        const int cx0 = min(max(x0, 0), Ww - 1), cx1 = min(max(x1, 0), Ww - 1);
        const int i00 = cy0 * Ww + cx0, i01 = cy0 * Ww + cx1;
        const int i10 = cy1 * Ww + cx0, i11 = cy1 * Ww + cx1;
#pragma unroll
        for (int c = 0; c < 8; ++c) {
          const float* pl = xg + (size_t)c * HW;
          const float s = w00 * pl[i00] + w01 * pl[i01] + w10 * pl[i10] + w11 * pl[i11];
          const float4 wv0 = *(const float4*)&wk[c * 8];
          const float4 wv1 = *(const float4*)&wk[c * 8 + 4];
          acc[0] = fmaf(s, wv0.x, acc[0]); acc[1] = fmaf(s, wv0.y, acc[1]);
          acc[2] = fmaf(s, wv0.z, acc[2]); acc[3] = fmaf(s, wv0.w, acc[3]);
          acc[4] = fmaf(s, wv1.x, acc[4]); acc[5] = fmaf(s, wv1.y, acc[5]);
          acc[6] = fmaf(s, wv1.z, acc[6]); acc[7] = fmaf(s, wv1.w, acc[7]);
        }
      }
    }
#pragma unroll
    for (int o = 0; o < 8; ++o) og[(size_t)o * HW] = act_f<ACT>(acc[o]);
  }
}

// ---------------------------------------------------------------------------
// Bilinear 2x upsample (unchanged)
// ---------------------------------------------------------------------------
__global__ void k_up2(const float* __restrict__ in, float* __restrict__ out,
                      int planes, int h, int w)
{
  const int ow = 2 * w, oh = 2 * h;
  const int total = planes * oh * ow;
  int idx = blockIdx.x * TPB + threadIdx.x;
  if (idx >= total) return;
  const int pl = idx / (oh * ow);
  const int rem = idx - pl * (oh * ow);
  const int oyj = rem / ow, oxj = rem - oyj * ow;
  int iy0, iy1, ix0, ix1; float wy0, wy1, wx0, wx1;
  if (oyj & 1) { iy0 = oyj >> 1; iy1 = min(iy0 + 1, h - 1); wy0 = 0.75f; wy1 = 0.25f; }
  else         { iy1 = oyj >> 1; iy0 = max(iy1 - 1, 0);     wy0 = 0.25f; wy1 = 0.75f; }
  if (oxj & 1) { ix0 = oxj >> 1; ix1 = min(ix0 + 1, w - 1); wx0 = 0.75f; wx1 = 0.25f; }
  else         { ix1 = oxj >> 1; ix0 = max(ix1 - 1, 0);     wx0 = 0.25f; wx1 = 0.75f; }
  const float* pp = in + (size_t)pl * h * w;
  out[idx] = wy0 * (wx0 * pp[iy0 * w + ix0] + wx1 * pp[iy0 * w + ix1])
           + wy1 * (wx0 * pp[iy1 * w + ix0] + wx1 * pp[iy1 * w + ix1]);
}

// ---------------------------------------------------------------------------
// host-side helpers (B = 2 fixed)
// ---------------------------------------------------------------------------
static void conv3(hipStream_t st, const float* in1, int c1, const float* in2, int c2,
                  const u16* wbuf, const float* b, float* out, int Cout, int h, int wd, int act)
{
  int cocols = (Cout + 63) / 64, Coutpad = cocols * 64;
  dim3 grid((h / 16) * (wd / 16), cocols, 2);
  if (act == 0)      k_conv_mfma<0><<<grid, TPB, 0, st>>>(in1, c1, in2, c2, wbuf, b, out, Cout, Coutpad, h, wd);
  else if (act == 1) k_conv_mfma<1><<<grid, TPB, 0, st>>>(in1, c1, in2, c2, wbuf, b, out, Cout, Coutpad, h, wd);
  else               k_conv_mfma<2><<<grid, TPB, 0, st>>>(in1, c1, in2, c2, wbuf, b, out, Cout, Coutpad, h, wd);
}

static void dconv(hipStream_t st, const float* x, const float* om, const float* mask,
                  int maskC, int maskBase, const float* w, const float* b, float* out,
                  int h, int wd, int sigm, int act)
{
  dim3 grid((h / 16) * (wd / 16), 2, 2);
  if (sigm) {
    if (act) k_dconv4<1,1><<<grid, TPB, 0, st>>>(x, om, mask, maskC, maskBase, w, b, out, h, wd);
    else     k_dconv4<1,0><<<grid, TPB, 0, st>>>(x, om, mask, maskC, maskBase, w, b, out, h, wd);
  } else     k_dconv4<0,0><<<grid, TPB, 0, st>>>(x, om, mask, maskC, maskBase, w, b, out, h, wd);
}

static void up2(hipStream_t st, const float* in, float* out, int h, int w)
{
  int total = 128 * 4 * h * w;
  k_up2<<<(total + TPB - 1) / TPB, TPB, 0, st>>>(in, out, 128, h, w);
}

extern "C" void kernel_launch(void* const* d_in, const int* in_sizes, int n_in,
                              void* d_out, int out_size, void* d_ws, size_t ws_size,
                              hipStream_t stream)
{
  const float* const* in = (const float* const*)d_in;
  const float* nrf0 = in[0]; const float* rf0 = in[1]; const float* swf0 = in[2];
  const float* nrf1 = in[3]; const float* rf1 = in[4]; const float* swf1 = in[5];
  const float* nrf2 = in[6]; const float* rf2 = in[7]; const float* swf2 = in[8];

  float* ws = (float*)d_ws;
  const size_t L0 = (size_t)2 * 64 * 192 * 192;    // 4,718,592 floats
  float* A   = ws;
  float* Bb  = A   + L0;
  float* U   = Bb  + L0;
  float* OM  = U   + L0;                           // 2*216*192*192
  float* EM  = OM  + (size_t)2 * 216 * 192 * 192;  // 2*72*192*192
  float* of1 = EM  + (size_t)2 * 72 * 192 * 192;
  float* dn1 = of1 + L0 / 4;
  float* of2 = dn1 + L0 / 4;
  float* dn2 = of2 + L0 / 16;
  u16*   wp  = (u16*)(dn2 + L0 / 16);              // bf16 weight buffers

  float* dout = (float*)d_out;
  float* out0 = dout;
  float* sh0  = dout + L0;
  float* sh1  = sh0  + L0;
  float* sh2  = sh1  + L0 / 4;

  // ---- single-launch weight prep for all 22 convs ----
  struct { int arg, cin, cout; } plist[22] = {
    {9,128,64},{11,64,64},{13,64,216},{15,128,64},{17,64,72},
    {21,128,64},{23,64,64},{25,64,216},{27,128,64},{29,64,72},
    {33,128,64},{35,64,64},{37,64,216},{39,128,64},{41,64,72},
    {45,128,64},{47,128,64},{49,128,64},{51,128,64},
    {53,128,64},{55,64,64},{57,64,216}};
  WPrepArgs wa;
  u16* wptr[22];
  int maxtot = 0;
  for (int i = 0; i < 22; ++i) {
    int cin = plist[i].cin, cout = plist[i].cout;
    int cpad = ((cout + 63) / 64) * 64;
    int tot = (cin / 32) * 9 * 2 * cpad * 40;
    wa.src[i] = in[plist[i].arg]; wa.dst[i] = wp;
    wa.cin[i] = cin; wa.cout[i] = cout; wa.coutpad[i] = cpad; wa.total[i] = tot;
    wptr[i] = wp; wp += tot;
    if (tot > maxtot) maxtot = tot;
  }
  k_wprep_all<<<dim3((maxtot + TPB - 1) / TPB, 22), TPB, 0, stream>>>(wa);

  u16* w_ocf0 = wptr[0];  u16* w_ocl0 = wptr[1];  u16* w_com0 = wptr[2];
  u16* w_em10 = wptr[3];  u16* w_em20 = wptr[4];
  u16* w_ocf1 = wptr[5];  u16* w_ocl1 = wptr[6];  u16* w_com1 = wptr[7];
  u16* w_em11 = wptr[8];  u16* w_em21 = wptr[9];
  u16* w_ocf2 = wptr[10]; u16* w_ocl2 = wptr[11]; u16* w_com2 = wptr[12];
  u16* w_em12 = wptr[13]; u16* w_em22 = wptr[14];
  u16* w_occ0 = wptr[15]; u16* w_fcc0 = wptr[16];
  u16* w_occ1 = wptr[17]; u16* w_fcc1 = wptr[18];
  u16* w_cas1 = wptr[19]; u16* w_cas2 = wptr[20]; u16* w_casc = wptr[21];

  // ----- level 2 (48x48) -----
  const int h2 = 48;
  conv3(stream, nrf2, 64, rf2, 64,  w_ocf2, in[34], A,   64,  h2, h2, 1);
  conv3(stream, A,    64, 0,   0,   w_ocl2, in[36], of2, 64,  h2, h2, 1);
  conv3(stream, swf2, 64, 0,   0,   w_com2, in[38], OM,  216, h2, h2, 0);
  conv3(stream, of2,  64, swf2, 64, w_em12, in[40], Bb,  64,  h2, h2, 1);
  conv3(stream, Bb,   64, 0,   0,   w_em22, in[42], EM,  72,  h2, h2, 2);
  dconv(stream, of2,  OM, EM,  72, 0,   in[43], in[44], sh2, h2, h2, 0, 0);
  dconv(stream, nrf2, OM, OM, 216, 144, in[43], in[44], dn2, h2, h2, 1, 1);

  // ----- level 1 (96x96) -----
  const int h1 = 96;
  up2(stream, of2, U, h2, h2);
  conv3(stream, nrf1, 64, rf1, 64,  w_ocf1, in[22], A,   64,  h1, h1, 1);
  conv3(stream, A,    64, U,   64,  w_occ1, in[50], Bb,  64,  h1, h1, 1);
  conv3(stream, Bb,   64, 0,   0,   w_ocl1, in[24], of1, 64,  h1, h1, 1);
  conv3(stream, swf1, 64, 0,   0,   w_com1, in[26], OM,  216, h1, h1, 0);
  conv3(stream, of1,  64, swf1, 64, w_em11, in[28], A,   64,  h1, h1, 1);
  conv3(stream, A,    64, 0,   0,   w_em21, in[30], EM,  72,  h1, h1, 2);
  dconv(stream, of1,  OM, EM,  72, 0,   in[31], in[32], sh1, h1, h1, 0, 0);
  dconv(stream, nrf1, OM, OM, 216, 144, in[31], in[32], A,   h1, h1, 1, 0);
  up2(stream, dn2, U, h2, h2);
  conv3(stream, A,    64, U,   64,  w_fcc1, in[52], dn1, 64,  h1, h1, 1);

  // ----- level 0 (192x192) -----
  const int h0 = 192;
  up2(stream, of1, U, h1, h1);
  conv3(stream, nrf0, 64, rf0, 64,  w_ocf0, in[10], A,   64,  h0, h0, 1);
  conv3(stream, A,    64, U,   64,  w_occ0, in[46], Bb,  64,  h0, h0, 1);
  conv3(stream, Bb,   64, 0,   0,   w_ocl0, in[12], A,   64,  h0, h0, 1);
  conv3(stream, swf0, 64, 0,   0,   w_com0, in[14], OM,  216, h0, h0, 0);
  conv3(stream, A,    64, swf0, 64, w_em10, in[16], Bb,  64,  h0, h0, 1);
  conv3(stream, Bb,   64, 0,   0,   w_em20, in[18], EM,  72,  h0, h0, 2);
  dconv(stream, A,    OM, EM,  72, 0,   in[19], in[20], sh0, h0, h0, 0, 0);
  dconv(stream, nrf0, OM, OM, 216, 144, in[19], in[20], Bb,  h0, h0, 1, 0);
  up2(stream, dn1, U, h1, h1);
  conv3(stream, Bb,   64, U,   64,  w_fcc0, in[48], A,   64,  h0, h0, 0);
  conv3(stream, A,    64, rf0, 64,  w_cas1, in[54], Bb,  64,  h0, h0, 1);
  conv3(stream, Bb,   64, 0,   0,   w_cas2, in[56], U,   64,  h0, h0, 1);
  conv3(stream, U,    64, 0,   0,   w_casc, in[58], OM,  216, h0, h0, 0);
  dconv(stream, A,    OM, OM, 216, 144, in[59], in[60], out0, h0, h0, 1, 1);
}

// Round 6
// 1726.808 us; speedup vs baseline: 1.4197x; 1.4197x over previous
//
#include <hip/hip_runtime.h>
#include <cstddef>
#include <cstdint>

#define TPB 256

typedef unsigned int u32;
typedef unsigned short u16;
typedef __bf16 bf16x8 __attribute__((ext_vector_type(8)));
typedef float f32x4 __attribute__((ext_vector_type(4)));

template<int ACT>
__device__ __forceinline__ float act_f(float v) {
  if (ACT == 1) return v >= 0.f ? v : 0.1f * v;          // lrelu
  if (ACT == 2) return 1.f / (1.f + expf(-v));           // sigmoid
  return v;
}

__device__ __forceinline__ u16 f2bf(float f) {           // fp32 -> bf16 RNE
  u32 u = __float_as_uint(f);
  u32 r = u + 0x7FFFu + ((u >> 16) & 1u);
  return (u16)(r >> 16);
}
__device__ __forceinline__ float bf2f(u16 h) {
  return __uint_as_float(((u32)h) << 16);
}

// ---------------------------------------------------------------------------
// Weight prep (single launch for all 22 convs): fp32 [Cout][Cin][3][3] ->
// bf16 hi/lo planes as [kc][tap][plane][co(pad)][40].  blockIdx.y = segment.
// ---------------------------------------------------------------------------
struct WPrepArgs {
  const float* src[22];
  u16* dst[22];
  int cin[22], cout[22], coutpad[22], total[22];
};

__global__ void k_wprep_all(WPrepArgs a)
{
  const int seg = blockIdx.y;
  const int idx = blockIdx.x * TPB + threadIdx.x;
  if (idx >= a.total[seg]) return;
  const int Cin = a.cin[seg], Cout = a.cout[seg], Coutpad = a.coutpad[seg];
  int kk = idx % 40; int t = idx / 40;
  int co = t % Coutpad; t /= Coutpad;
  int plane = t & 1; t >>= 1;
  int tap = t % 9; int kc = t / 9;
  u16 v = 0;
  if (kk < 32 && co < Cout) {
    float w0 = a.src[seg][((size_t)co * Cin + kc * 32 + kk) * 9 + tap];
    u16 hi = f2bf(w0);
    v = plane ? f2bf(w0 - bf2f(hi)) : hi;
  }
  a.dst[seg][idx] = v;
}

// ---------------------------------------------------------------------------
// 3x3 conv via MFMA bf16 3-pass split (unchanged from round 2).
// ---------------------------------------------------------------------------
template<int ACT>
__global__ __launch_bounds__(TPB, 2)
void k_conv_mfma(const float* __restrict__ in1, int c1,
                 const float* __restrict__ in2, int c2,
                 const u16* __restrict__ wbuf, const float* __restrict__ bias,
                 float* __restrict__ out, int Cout, int Coutpad, int Hh, int Ww)
{
  __shared__ __align__(16) u16 s_act[18 * 18 * 72];
  __shared__ __align__(16) u16 s_w[3 * 2 * 64 * 40];
  const int Cin = c1 + c2;
  const int b   = blockIdx.z;
  const int cb  = blockIdx.y << 6;
  const int xt  = Ww >> 4;
  const int by0 = (blockIdx.x / xt) << 4;
  const int bx0 = (blockIdx.x % xt) << 4;
  const int tid = threadIdx.x;
  const int lx = tid & 15, slot = (tid >> 4) & 3, wv = tid >> 6;
  const int HW = Hh * Ww;

  f32x4 acc[4][4];
#pragma unroll
  for (int i = 0; i < 4; ++i)
#pragma unroll
    for (int j = 0; j < 4; ++j) acc[i][j] = (f32x4){0.f, 0.f, 0.f, 0.f};

#pragma unroll 1
  for (int kc = 0; kc < (Cin >> 5); ++kc) {
    __syncthreads();
    // ---- stage activations: 18x18 positions x 32 ci, fp32 -> bf16 hi/lo ----
    {
      const int cbase = kc << 5;
      const float* sp = (cbase < c1) ? in1 + ((size_t)b * c1 + cbase) * HW
                                     : in2 + ((size_t)b * c2 + (cbase - c1)) * HW;
#pragma unroll 1
      for (int u = tid; u < 324; u += TPB) {
        int y = u / 18, x = u - y * 18;
        int gy = by0 - 1 + y, gx = bx0 - 1 + x;
        bool inb = ((unsigned)gy < (unsigned)Hh) & ((unsigned)gx < (unsigned)Ww);
        const float msk = inb ? 1.f : 0.f;
        const size_t poff = inb ? ((size_t)gy * Ww + gx) : 0;
        const float* s0 = sp + poff;
        u16* dp = &s_act[(y * 18 + x) * 72];
#pragma unroll
        for (int c8 = 0; c8 < 4; ++c8) {
          u32 hb[4], lb[4];
#pragma unroll
          for (int j = 0; j < 4; ++j) {
            float a0 = s0[(size_t)(c8 * 8 + 2 * j) * HW] * msk;
            float a1 = s0[(size_t)(c8 * 8 + 2 * j + 1) * HW] * msk;
            u16 h0 = f2bf(a0), h1 = f2bf(a1);
            hb[j] = (u32)h0 | ((u32)h1 << 16);
            lb[j] = (u32)f2bf(a0 - bf2f(h0)) | ((u32)f2bf(a1 - bf2f(h1)) << 16);
          }
          *(uint4*)&dp[c8 * 8]      = make_uint4(hb[0], hb[1], hb[2], hb[3]);
          *(uint4*)&dp[32 + c8 * 8] = make_uint4(lb[0], lb[1], lb[2], lb[3]);
        }
      }
    }
#pragma unroll 1
    for (int ky = 0; ky < 3; ++ky) {
      __syncthreads();
      {
        const size_t segstride = (size_t)Coutpad * 40;
        const size_t tb = (size_t)((kc * 9 + ky * 3) * 2) * segstride + (size_t)cb * 40;
#pragma unroll 1
        for (int i = tid; i < 1920; i += TPB) {
          int seg = i / 320, j = i - seg * 320;
          const uint4 v = *(const uint4*)&wbuf[tb + (size_t)seg * segstride + j * 8];
          *(uint4*)&s_w[seg * 2560 + j * 8] = v;
        }
      }
      __syncthreads();
#pragma unroll
      for (int kx = 0; kx < 3; ++kx) {
        bf16x8 Af[4][2], Bf[4][2];
#pragma unroll
        for (int ct = 0; ct < 4; ++ct)
#pragma unroll
          for (int p = 0; p < 2; ++p)
            Af[ct][p] = *(const bf16x8*)&s_w[((kx * 2 + p) * 64 + ct * 16 + lx) * 40 + slot * 8];
#pragma unroll
        for (int pg = 0; pg < 4; ++pg)
#pragma unroll
          for (int p = 0; p < 2; ++p)
            Bf[pg][p] = *(const bf16x8*)&s_act[((wv * 4 + pg + ky) * 18 + lx + kx) * 72 + p * 32 + slot * 8];
#pragma unroll
        for (int ct = 0; ct < 4; ++ct)
#pragma unroll
          for (int pg = 0; pg < 4; ++pg) {
            acc[ct][pg] = __builtin_amdgcn_mfma_f32_16x16x32_bf16(Af[ct][0], Bf[pg][0], acc[ct][pg], 0, 0, 0);
            acc[ct][pg] = __builtin_amdgcn_mfma_f32_16x16x32_bf16(Af[ct][1], Bf[pg][0], acc[ct][pg], 0, 0, 0);
            acc[ct][pg] = __builtin_amdgcn_mfma_f32_16x16x32_bf16(Af[ct][0], Bf[pg][1], acc[ct][pg], 0, 0, 0);
          }
      }
    }
  }
  const int ox = bx0 + lx;
#pragma unroll
  for (int ct = 0; ct < 4; ++ct) {
    const int co0 = cb + ct * 16 + slot * 4;
#pragma unroll
    for (int r = 0; r < 4; ++r) {
      const int co = co0 + r;
      if (co < Cout) {
        const float bv = bias[co];
        float* op = out + ((size_t)b * Cout + co) * HW + (size_t)(by0 + wv * 4) * Ww + ox;
#pragma unroll
        for (int pg = 0; pg < 4; ++pg)
          op[pg * Ww] = act_f<ACT>(acc[ct][pg][r] + bv);
      }
    }
  }
}

// ---------------------------------------------------------------------------
// Modulated deformable 3x3 conv, v5: 16x8 tile, 4 groups/block (blockIdx.y),
// channel-last LDS x-tile [240 px][40] (32ch + 8 pad) in bf16 -> each bilinear
// corner is ONE ds_read_b128 (8 ch). Grid @192^2 = 1152 blocks. 256 threads =
// 128 px x 2 group-slots. Tap loop unrolled, om reads inline (no scratch).
// ---------------------------------------------------------------------------
template<int SIGM, int ACT>
__global__ __launch_bounds__(TPB, 4)
void k_dconv5(const float* __restrict__ x,
              const float* __restrict__ off,
              const float* __restrict__ mask, int maskC, int maskBase,
              const float* __restrict__ wgt, const float* __restrict__ bias,
              float* __restrict__ out, int Hh, int Ww)
{
  __shared__ __align__(16) u16 s_x[240][40];        // [12 rows x 20 cols][32ch+pad]
  __shared__ __align__(16) float s_w[4 * 9 * 64];   // [gl][k][c][o]
  __shared__ float s_b[32];
  const int b   = blockIdx.z;
  const int gs  = blockIdx.y;                       // group half: gs*4..gs*4+3
  const int xt  = Ww >> 4;
  const int ty0 = (blockIdx.x / xt) << 3;
  const int tx0 = (blockIdx.x % xt) << 4;
  const int tid = threadIdx.x;
  const int HW  = Hh * Ww;

  for (int i = tid; i < 2304; i += TPB) {
    int o = i & 7, c = (i >> 3) & 7, k = (i >> 6) % 9, gl = i / 576;
    s_w[i] = wgt[(((size_t)((gs * 4 + gl) * 8 + o)) * 8 + c) * 9 + k];
  }
  if (tid < 32) s_b[tid] = bias[gs * 32 + tid];
  // stage x: 12x20 halo region, 32 channels, channel-last
  {
    const float* xb = x + ((size_t)b * 64 + gs * 32) * HW;
    for (int i = tid; i < 240 * 32; i += TPB) {
      int c = i / 240, px = i - c * 240;
      int r = px / 20, cx = px - r * 20;
      int gy = ty0 - 2 + r, gx = tx0 - 2 + cx;
      float v = 0.f;
      if ((unsigned)gy < (unsigned)Hh && (unsigned)gx < (unsigned)Ww)
        v = xb[(size_t)c * HW + gy * Ww + gx];
      s_x[px][c] = f2bf(v);
    }
  }
  __syncthreads();

  const int pin = tid & 127;
  const int ghalf = tid >> 7;                       // 0..1 -> handles 2 groups
  const int py_ = pin >> 4, px_ = pin & 15;
  const int gy = ty0 + py_, gx = tx0 + px_;
  const int p  = gy * Ww + gx;

#pragma unroll
  for (int j = 0; j < 2; ++j) {
    const int gl = ghalf * 2 + j;
    const int g  = gs * 4 + gl;
    const float* ob = off  + ((size_t)b * 216 + g * 18) * HW + p;
    const float* mb = mask + ((size_t)b * maskC + maskBase + g * 9) * HW + p;
    const float* xg = x    + ((size_t)b * 64 + g * 8) * HW;
    float*       og = out  + ((size_t)b * 64 + g * 8) * HW + p;
    const float* wg = &s_w[gl * 9 * 64];

    float acc[8];
#pragma unroll
    for (int o = 0; o < 8; ++o) acc[o] = s_b[gl * 8 + o];

#pragma unroll
    for (int k = 0; k < 9; ++k) {
      const float oyk = ob[(size_t)(2 * k) * HW];
      const float oxk = ob[(size_t)(2 * k + 1) * HW];
      float m = mb[(size_t)k * HW];
      if (SIGM) m = 1.f / (1.f + expf(-m));
      const float py = (float)(gy + k / 3 - 1) + oyk;
      const float px = (float)(gx + k % 3 - 1) + oxk;
      const float y0f = floorf(py), x0f = floorf(px);
      const float fy = py - y0f, fx = px - x0f;
      const int y0 = (int)y0f, x0 = (int)x0f;
      const int y1 = y0 + 1, x1 = x0 + 1;
      const float vy0 = (y0 >= 0 && y0 < Hh) ? 1.f : 0.f;
      const float vy1 = (y1 >= 0 && y1 < Hh) ? 1.f : 0.f;
      const float vx0 = (x0 >= 0 && x0 < Ww) ? 1.f : 0.f;
      const float vx1 = (x1 >= 0 && x1 < Ww) ? 1.f : 0.f;
      const float w00 = (1.f - fy) * (1.f - fx) * vy0 * vx0 * m;
      const float w01 = (1.f - fy) * fx * vy0 * vx1 * m;
      const float w10 = fy * (1.f - fx) * vy1 * vx0 * m;
      const float w11 = fy * fx * vy1 * vx1 * m;
      const float* wk = &wg[k * 64];
      const int ly = y0 - ty0 + 2, lxw = x0 - tx0 + 2;
      if ((unsigned)ly < 11u && (unsigned)lxw < 19u) {
        const u16* base = &s_x[ly * 20 + lxw][gl * 8];
        const bf16x8 c00 = *(const bf16x8*)base;
        const bf16x8 c01 = *(const bf16x8*)(base + 40);
        const bf16x8 c10 = *(const bf16x8*)(base + 800);
        const bf16x8 c11 = *(const bf16x8*)(base + 840);
#pragma unroll
        for (int c = 0; c < 8; ++c) {
          const float s = w00 * (float)c00[c] + w01 * (float)c01[c]
                        + w10 * (float)c10[c] + w11 * (float)c11[c];
          const float4 wv0 = *(const float4*)&wk[c * 8];
          const float4 wv1 = *(const float4*)&wk[c * 8 + 4];
          acc[0] = fmaf(s, wv0.x, acc[0]); acc[1] = fmaf(s, wv0.y, acc[1]);
          acc[2] = fmaf(s, wv0.z, acc[2]); acc[3] = fmaf(s, wv0.w, acc[3]);
          acc[4] = fmaf(s, wv1.x, acc[4]); acc[5] = fmaf(s, wv1.y, acc[5]);
          acc[6] = fmaf(s, wv1.z, acc[6]); acc[7] = fmaf(s, wv1.w, acc[7]);
        }
      } else {
        const int cy0 = min(max(y0, 0), Hh - 1), cy1 = min(max(y1, 0), Hh - 1);
        const int cx0 = min(max(x0, 0), Ww - 1), cx1 = min(max(x1, 0), Ww - 1);
        const int i00 = cy0 * Ww + cx0, i01 = cy0 * Ww + cx1;
        const int i10 = cy1 * Ww + cx0, i11 = cy1 * Ww + cx1;
#pragma unroll
        for (int c = 0; c < 8; ++c) {
          const float* pl = xg + (size_t)c * HW;
          const float s = w00 * pl[i00] + w01 * pl[i01] + w10 * pl[i10] + w11 * pl[i11];
          const float4 wv0 = *(const float4*)&wk[c * 8];
          const float4 wv1 = *(const float4*)&wk[c * 8 + 4];
          acc[0] = fmaf(s, wv0.x, acc[0]); acc[1] = fmaf(s, wv0.y, acc[1]);
          acc[2] = fmaf(s, wv0.z, acc[2]); acc[3] = fmaf(s, wv0.w, acc[3]);
          acc[4] = fmaf(s, wv1.x, acc[4]); acc[5] = fmaf(s, wv1.y, acc[5]);
          acc[6] = fmaf(s, wv1.z, acc[6]); acc[7] = fmaf(s, wv1.w, acc[7]);
        }
      }
    }
#pragma unroll
    for (int o = 0; o < 8; ++o) og[(size_t)o * HW] = act_f<ACT>(acc[o]);
  }
}

// ---------------------------------------------------------------------------
// Bilinear 2x upsample (unchanged)
// ---------------------------------------------------------------------------
__global__ void k_up2(const float* __restrict__ in, float* __restrict__ out,
                      int planes, int h, int w)
{
  const int ow = 2 * w, oh = 2 * h;
  const int total = planes * oh * ow;
  int idx = blockIdx.x * TPB + threadIdx.x;
  if (idx >= total) return;
  const int pl = idx / (oh * ow);
  const int rem = idx - pl * (oh * ow);
  const int oyj = rem / ow, oxj = rem - oyj * ow;
  int iy0, iy1, ix0, ix1; float wy0, wy1, wx0, wx1;
  if (oyj & 1) { iy0 = oyj >> 1; iy1 = min(iy0 + 1, h - 1); wy0 = 0.75f; wy1 = 0.25f; }
  else         { iy1 = oyj >> 1; iy0 = max(iy1 - 1, 0);     wy0 = 0.25f; wy1 = 0.75f; }
  if (oxj & 1) { ix0 = oxj >> 1; ix1 = min(ix0 + 1, w - 1); wx0 = 0.75f; wx1 = 0.25f; }
  else         { ix1 = oxj >> 1; ix0 = max(ix1 - 1, 0);     wx0 = 0.25f; wx1 = 0.75f; }
  const float* pp = in + (size_t)pl * h * w;
  out[idx] = wy0 * (wx0 * pp[iy0 * w + ix0] + wx1 * pp[iy0 * w + ix1])
           + wy1 * (wx0 * pp[iy1 * w + ix0] + wx1 * pp[iy1 * w + ix1]);
}

// ---------------------------------------------------------------------------
// host-side helpers (B = 2 fixed)
// ---------------------------------------------------------------------------
static void conv3(hipStream_t st, const float* in1, int c1, const float* in2, int c2,
                  const u16* wbuf, const float* b, float* out, int Cout, int h, int wd, int act)
{
  int cocols = (Cout + 63) / 64, Coutpad = cocols * 64;
  dim3 grid((h / 16) * (wd / 16), cocols, 2);
  if (act == 0)      k_conv_mfma<0><<<grid, TPB, 0, st>>>(in1, c1, in2, c2, wbuf, b, out, Cout, Coutpad, h, wd);
  else if (act == 1) k_conv_mfma<1><<<grid, TPB, 0, st>>>(in1, c1, in2, c2, wbuf, b, out, Cout, Coutpad, h, wd);
  else               k_conv_mfma<2><<<grid, TPB, 0, st>>>(in1, c1, in2, c2, wbuf, b, out, Cout, Coutpad, h, wd);
}

static void dconv(hipStream_t st, const float* x, const float* om, const float* mask,
                  int maskC, int maskBase, const float* w, const float* b, float* out,
                  int h, int wd, int sigm, int act)
{
  dim3 grid((h / 8) * (wd / 16), 2, 2);
  if (sigm) {
    if (act) k_dconv5<1,1><<<grid, TPB, 0, st>>>(x, om, mask, maskC, maskBase, w, b, out, h, wd);
    else     k_dconv5<1,0><<<grid, TPB, 0, st>>>(x, om, mask, maskC, maskBase, w, b, out, h, wd);
  } else     k_dconv5<0,0><<<grid, TPB, 0, st>>>(x, om, mask, maskC, maskBase, w, b, out, h, wd);
}

static void up2(hipStream_t st, const float* in, float* out, int h, int w)
{
  int total = 128 * 4 * h * w;
  k_up2<<<(total + TPB - 1) / TPB, TPB, 0, st>>>(in, out, 128, h, w);
}

extern "C" void kernel_launch(void* const* d_in, const int* in_sizes, int n_in,
                              void* d_out, int out_size, void* d_ws, size_t ws_size,
                              hipStream_t stream)
{
  const float* const* in = (const float* const*)d_in;
  const float* nrf0 = in[0]; const float* rf0 = in[1]; const float* swf0 = in[2];
  const float* nrf1 = in[3]; const float* rf1 = in[4]; const float* swf1 = in[5];
  const float* nrf2 = in[6]; const float* rf2 = in[7]; const float* swf2 = in[8];

  float* ws = (float*)d_ws;
  const size_t L0 = (size_t)2 * 64 * 192 * 192;    // 4,718,592 floats
  float* A   = ws;
  float* Bb  = A   + L0;
  float* U   = Bb  + L0;
  float* OM  = U   + L0;                           // 2*216*192*192
  float* EM  = OM  + (size_t)2 * 216 * 192 * 192;  // 2*72*192*192
  float* of1 = EM  + (size_t)2 * 72 * 192 * 192;
  float* dn1 = of1 + L0 / 4;
  float* of2 = dn1 + L0 / 4;
  float* dn2 = of2 + L0 / 16;
  u16*   wp  = (u16*)(dn2 + L0 / 16);              // bf16 weight buffers

  float* dout = (float*)d_out;
  float* out0 = dout;
  float* sh0  = dout + L0;
  float* sh1  = sh0  + L0;
  float* sh2  = sh1  + L0 / 4;

  // ---- single-launch weight prep for all 22 convs ----
  struct { int arg, cin, cout; } plist[22] = {
    {9,128,64},{11,64,64},{13,64,216},{15,128,64},{17,64,72},
    {21,128,64},{23,64,64},{25,64,216},{27,128,64},{29,64,72},
    {33,128,64},{35,64,64},{37,64,216},{39,128,64},{41,64,72},
    {45,128,64},{47,128,64},{49,128,64},{51,128,64},
    {53,128,64},{55,64,64},{57,64,216}};
  WPrepArgs wa;
  u16* wptr[22];
  int maxtot = 0;
  for (int i = 0; i < 22; ++i) {
    int cin = plist[i].cin, cout = plist[i].cout;
    int cpad = ((cout + 63) / 64) * 64;
    int tot = (cin / 32) * 9 * 2 * cpad * 40;
    wa.src[i] = in[plist[i].arg]; wa.dst[i] = wp;
    wa.cin[i] = cin; wa.cout[i] = cout; wa.coutpad[i] = cpad; wa.total[i] = tot;
    wptr[i] = wp; wp += tot;
    if (tot > maxtot) maxtot = tot;
  }
  k_wprep_all<<<dim3((maxtot + TPB - 1) / TPB, 22), TPB, 0, stream>>>(wa);

  u16* w_ocf0 = wptr[0];  u16* w_ocl0 = wptr[1];  u16* w_com0 = wptr[2];
  u16* w_em10 = wptr[3];  u16* w_em20 = wptr[4];
  u16* w_ocf1 = wptr[5];  u16* w_ocl1 = wptr[6];  u16* w_com1 = wptr[7];
  u16* w_em11 = wptr[8];  u16* w_em21 = wptr[9];
  u16* w_ocf2 = wptr[10]; u16* w_ocl2 = wptr[11]; u16* w_com2 = wptr[12];
  u16* w_em12 = wptr[13]; u16* w_em22 = wptr[14];
  u16* w_occ0 = wptr[15]; u16* w_fcc0 = wptr[16];
  u16* w_occ1 = wptr[17]; u16* w_fcc1 = wptr[18];
  u16* w_cas1 = wptr[19]; u16* w_cas2 = wptr[20]; u16* w_casc = wptr[21];

  // ----- level 2 (48x48) -----
  const int h2 = 48;
  conv3(stream, nrf2, 64, rf2, 64,  w_ocf2, in[34], A,   64,  h2, h2, 1);
  conv3(stream, A,    64, 0,   0,   w_ocl2, in[36], of2, 64,  h2, h2, 1);
  conv3(stream, swf2, 64, 0,   0,   w_com2, in[38], OM,  216, h2, h2, 0);
  conv3(stream, of2,  64, swf2, 64, w_em12, in[40], Bb,  64,  h2, h2, 1);
  conv3(stream, Bb,   64, 0,   0,   w_em22, in[42], EM,  72,  h2, h2, 2);
  dconv(stream, of2,  OM, EM,  72, 0,   in[43], in[44], sh2, h2, h2, 0, 0);
  dconv(stream, nrf2, OM, OM, 216, 144, in[43], in[44], dn2, h2, h2, 1, 1);

  // ----- level 1 (96x96) -----
  const int h1 = 96;
  up2(stream, of2, U, h2, h2);
  conv3(stream, nrf1, 64, rf1, 64,  w_ocf1, in[22], A,   64,  h1, h1, 1);
  conv3(stream, A,    64, U,   64,  w_occ1, in[50], Bb,  64,  h1, h1, 1);
  conv3(stream, Bb,   64, 0,   0,   w_ocl1, in[24], of1, 64,  h1, h1, 1);
  conv3(stream, swf1, 64, 0,   0,   w_com1, in[26], OM,  216, h1, h1, 0);
  conv3(stream, of1,  64, swf1, 64, w_em11, in[28], A,   64,  h1, h1, 1);
  conv3(stream, A,    64, 0,   0,   w_em21, in[30], EM,  72,  h1, h1, 2);
  dconv(stream, of1,  OM, EM,  72, 0,   in[31], in[32], sh1, h1, h1, 0, 0);
  dconv(stream, nrf1, OM, OM, 216, 144, in[31], in[32], A,   h1, h1, 1, 0);
  up2(stream, dn2, U, h2, h2);
  conv3(stream, A,    64, U,   64,  w_fcc1, in[52], dn1, 64,  h1, h1, 1);

  // ----- level 0 (192x192) -----
  const int h0 = 192;
  up2(stream, of1, U, h1, h1);
  conv3(stream, nrf0, 64, rf0, 64,  w_ocf0, in[10], A,   64,  h0, h0, 1);
  conv3(stream, A,    64, U,   64,  w_occ0, in[46], Bb,  64,  h0, h0, 1);
  conv3(stream, Bb,   64, 0,   0,   w_ocl0, in[12], A,   64,  h0, h0, 1);
  conv3(stream, swf0, 64, 0,   0,   w_com0, in[14], OM,  216, h0, h0, 0);
  conv3(stream, A,    64, swf0, 64, w_em10, in[16], Bb,  64,  h0, h0, 1);
  conv3(stream, Bb,   64, 0,   0,   w_em20, in[18], EM,  72,  h0, h0, 2);
  dconv(stream, A,    OM, EM,  72, 0,   in[19], in[20], sh0, h0, h0, 0, 0);
  dconv(stream, nrf0, OM, OM, 216, 144, in[19], in[20], Bb,  h0, h0, 1, 0);
  up2(stream, dn1, U, h1, h1);
  conv3(stream, Bb,   64, U,   64,  w_fcc0, in[48], A,   64,  h0, h0, 0);
  conv3(stream, A,    64, rf0, 64,  w_cas1, in[54], Bb,  64,  h0, h0, 1);
  conv3(stream, Bb,   64, 0,   0,   w_cas2, in[56], U,   64,  h0, h0, 1);
  conv3(stream, U,    64, 0,   0,   w_casc, in[58], OM,  216, h0, h0, 0);
  dconv(stream, A,    OM, OM, 216, 144, in[59], in[60], out0, h0, h0, 1, 1);
}

// Round 7
// 1213.113 us; speedup vs baseline: 2.0209x; 1.4235x over previous
//
#include <hip/hip_runtime.h>
#include <cstddef>
#include <cstdint>

#define TPB 256

typedef unsigned int u32;
typedef unsigned short u16;
typedef __bf16 bf16x8 __attribute__((ext_vector_type(8)));
typedef float f32x4 __attribute__((ext_vector_type(4)));

template<int ACT>
__device__ __forceinline__ float act_f(float v) {
  if (ACT == 1) return v >= 0.f ? v : 0.1f * v;          // lrelu
  if (ACT == 2) return 1.f / (1.f + expf(-v));           // sigmoid
  return v;
}

__device__ __forceinline__ u16 f2bf(float f) {           // fp32 -> bf16 RNE
  u32 u = __float_as_uint(f);
  u32 r = u + 0x7FFFu + ((u >> 16) & 1u);
  return (u16)(r >> 16);
}
__device__ __forceinline__ float bf2f(u16 h) {
  return __uint_as_float(((u32)h) << 16);
}

// ---------------------------------------------------------------------------
// Weight prep (single launch, all 22 convs): fp32 [Cout][Cin][3][3] -> bf16
// single plane laid out as [kc][tap][co(pad)][40].  blockIdx.y = segment.
// ---------------------------------------------------------------------------
struct WPrepArgs {
  const float* src[22];
  u16* dst[22];
  int cin[22], cout[22], coutpad[22], total[22];
};

__global__ void k_wprep_all(WPrepArgs a)
{
  const int seg = blockIdx.y;
  const int idx = blockIdx.x * TPB + threadIdx.x;
  if (idx >= a.total[seg]) return;
  const int Cin = a.cin[seg], Cout = a.cout[seg], Coutpad = a.coutpad[seg];
  int kk = idx % 40; int t = idx / 40;
  int co = t % Coutpad; t /= Coutpad;
  int tap = t % 9; int kc = t / 9;
  u16 v = 0;
  if (kk < 32 && co < Cout)
    v = f2bf(a.src[seg][((size_t)co * Cin + kc * 32 + kk) * 9 + tap]);
  a.dst[seg][idx] = v;
}

// ---------------------------------------------------------------------------
// 3x3 conv via MFMA bf16, SINGLE-PASS (v3). Block: 16x16 px x 64 co, 4 waves.
// Act LDS: [18*18 px][40] bf16 (32ch + 8 pad; 80B stride, 16B-aligned b128).
// W   LDS: [3 kx][64 co][40] bf16. Total ~41KB -> 3 blocks/CU.
// Per kx per wave: 4 A b128 + 4 B b128 + 16 MFMA.
// ---------------------------------------------------------------------------
template<int ACT>
__global__ __launch_bounds__(TPB, 3)
void k_conv_mfma(const float* __restrict__ in1, int c1,
                 const float* __restrict__ in2, int c2,
                 const u16* __restrict__ wbuf, const float* __restrict__ bias,
                 float* __restrict__ out, int Cout, int Coutpad, int Hh, int Ww)
{
  __shared__ __align__(16) u16 s_act[18 * 18 * 40];
  __shared__ __align__(16) u16 s_w[3 * 64 * 40];
  const int Cin = c1 + c2;
  const int b   = blockIdx.z;
  const int cb  = blockIdx.y << 6;
  const int xt  = Ww >> 4;
  const int by0 = (blockIdx.x / xt) << 4;
  const int bx0 = (blockIdx.x % xt) << 4;
  const int tid = threadIdx.x;
  const int lx = tid & 15, slot = (tid >> 4) & 3, wv = tid >> 6;
  const int HW = Hh * Ww;

  f32x4 acc[4][4];
#pragma unroll
  for (int i = 0; i < 4; ++i)
#pragma unroll
    for (int j = 0; j < 4; ++j) acc[i][j] = (f32x4){0.f, 0.f, 0.f, 0.f};

#pragma unroll 1
  for (int kc = 0; kc < (Cin >> 5); ++kc) {
    __syncthreads();
    // ---- stage activations: 18x18 positions x 32 ci, fp32 -> bf16 ----
    {
      const int cbase = kc << 5;
      const float* sp = (cbase < c1) ? in1 + ((size_t)b * c1 + cbase) * HW
                                     : in2 + ((size_t)b * c2 + (cbase - c1)) * HW;
#pragma unroll 1
      for (int u = tid; u < 324; u += TPB) {
        int y = u / 18, x = u - y * 18;
        int gy = by0 - 1 + y, gx = bx0 - 1 + x;
        bool inb = ((unsigned)gy < (unsigned)Hh) & ((unsigned)gx < (unsigned)Ww);
        const float msk = inb ? 1.f : 0.f;
        const size_t poff = inb ? ((size_t)gy * Ww + gx) : 0;
        const float* s0 = sp + poff;
        u16* dp = &s_act[u * 40];
#pragma unroll
        for (int c8 = 0; c8 < 4; ++c8) {
          u32 hb[4];
#pragma unroll
          for (int j = 0; j < 4; ++j) {
            float a0 = s0[(size_t)(c8 * 8 + 2 * j) * HW] * msk;
            float a1 = s0[(size_t)(c8 * 8 + 2 * j + 1) * HW] * msk;
            hb[j] = (u32)f2bf(a0) | ((u32)f2bf(a1) << 16);
          }
          *(uint4*)&dp[c8 * 8] = make_uint4(hb[0], hb[1], hb[2], hb[3]);
        }
      }
    }
#pragma unroll 1
    for (int ky = 0; ky < 3; ++ky) {
      __syncthreads();
      // ---- stage weights for this ky: [3 kx][64 co][40 k] ----
      {
        const size_t base = ((size_t)(kc * 9 + ky * 3) * Coutpad + cb) * 40;
        const size_t tapstride = (size_t)Coutpad * 40;
#pragma unroll 1
        for (int i = tid; i < 960; i += TPB) {           // 960 uint4 = 7680 u16
          int kxl = i / 320, j = i - kxl * 320;
          const uint4 v = *(const uint4*)&wbuf[base + (size_t)kxl * tapstride + j * 8];
          *(uint4*)&s_w[kxl * 2560 + j * 8] = v;
        }
      }
      __syncthreads();
#pragma unroll
      for (int kx = 0; kx < 3; ++kx) {
        bf16x8 Af[4], Bf[4];
#pragma unroll
        for (int ct = 0; ct < 4; ++ct)
          Af[ct] = *(const bf16x8*)&s_w[(kx * 64 + ct * 16 + lx) * 40 + slot * 8];
#pragma unroll
        for (int pg = 0; pg < 4; ++pg)
          Bf[pg] = *(const bf16x8*)&s_act[((wv * 4 + pg + ky) * 18 + lx + kx) * 40 + slot * 8];
#pragma unroll
        for (int ct = 0; ct < 4; ++ct)
#pragma unroll
          for (int pg = 0; pg < 4; ++pg)
            acc[ct][pg] = __builtin_amdgcn_mfma_f32_16x16x32_bf16(Af[ct], Bf[pg], acc[ct][pg], 0, 0, 0);
      }
    }
  }
  const int ox = bx0 + lx;
#pragma unroll
  for (int ct = 0; ct < 4; ++ct) {
    const int co0 = cb + ct * 16 + slot * 4;
#pragma unroll
    for (int r = 0; r < 4; ++r) {
      const int co = co0 + r;
      if (co < Cout) {
        const float bv = bias[co];
        float* op = out + ((size_t)b * Cout + co) * HW + (size_t)(by0 + wv * 4) * Ww + ox;
#pragma unroll
        for (int pg = 0; pg < 4; ++pg)
          op[pg * Ww] = act_f<ACT>(acc[ct][pg][r] + bv);
      }
    }
  }
}

// ---------------------------------------------------------------------------
// Modulated deformable 3x3 conv, v5 (unchanged from round 6).
// ---------------------------------------------------------------------------
template<int SIGM, int ACT>
__global__ __launch_bounds__(TPB, 4)
void k_dconv5(const float* __restrict__ x,
              const float* __restrict__ off,
              const float* __restrict__ mask, int maskC, int maskBase,
              const float* __restrict__ wgt, const float* __restrict__ bias,
              float* __restrict__ out, int Hh, int Ww)
{
  __shared__ __align__(16) u16 s_x[240][40];        // [12 rows x 20 cols][32ch+pad]
  __shared__ __align__(16) float s_w[4 * 9 * 64];   // [gl][k][c][o]
  __shared__ float s_b[32];
  const int b   = blockIdx.z;
  const int gs  = blockIdx.y;                       // group half: gs*4..gs*4+3
  const int xt  = Ww >> 4;
  const int ty0 = (blockIdx.x / xt) << 3;
  const int tx0 = (blockIdx.x % xt) << 4;
  const int tid = threadIdx.x;
  const int HW  = Hh * Ww;

  for (int i = tid; i < 2304; i += TPB) {
    int o = i & 7, c = (i >> 3) & 7, k = (i >> 6) % 9, gl = i / 576;
    s_w[i] = wgt[(((size_t)((gs * 4 + gl) * 8 + o)) * 8 + c) * 9 + k];
  }
  if (tid < 32) s_b[tid] = bias[gs * 32 + tid];
  {
    const float* xb = x + ((size_t)b * 64 + gs * 32) * HW;
    for (int i = tid; i < 240 * 32; i += TPB) {
      int c = i / 240, px = i - c * 240;
      int r = px / 20, cx = px - r * 20;
      int gy = ty0 - 2 + r, gx = tx0 - 2 + cx;
      float v = 0.f;
      if ((unsigned)gy < (unsigned)Hh && (unsigned)gx < (unsigned)Ww)
        v = xb[(size_t)c * HW + gy * Ww + gx];
      s_x[px][c] = f2bf(v);
    }
  }
  __syncthreads();

  const int pin = tid & 127;
  const int ghalf = tid >> 7;
  const int py_ = pin >> 4, px_ = pin & 15;
  const int gy = ty0 + py_, gx = tx0 + px_;
  const int p  = gy * Ww + gx;

#pragma unroll
  for (int j = 0; j < 2; ++j) {
    const int gl = ghalf * 2 + j;
    const int g  = gs * 4 + gl;
    const float* ob = off  + ((size_t)b * 216 + g * 18) * HW + p;
    const float* mb = mask + ((size_t)b * maskC + maskBase + g * 9) * HW + p;
    const float* xg = x    + ((size_t)b * 64 + g * 8) * HW;
    float*       og = out  + ((size_t)b * 64 + g * 8) * HW + p;
    const float* wg = &s_w[gl * 9 * 64];

    float acc[8];
#pragma unroll
    for (int o = 0; o < 8; ++o) acc[o] = s_b[gl * 8 + o];

#pragma unroll
    for (int k = 0; k < 9; ++k) {
      const float oyk = ob[(size_t)(2 * k) * HW];
      const float oxk = ob[(size_t)(2 * k + 1) * HW];
      float m = mb[(size_t)k * HW];
      if (SIGM) m = 1.f / (1.f + expf(-m));
      const float py = (float)(gy + k / 3 - 1) + oyk;
      const float px = (float)(gx + k % 3 - 1) + oxk;
      const float y0f = floorf(py), x0f = floorf(px);
      const float fy = py - y0f, fx = px - x0f;
      const int y0 = (int)y0f, x0 = (int)x0f;
      const int y1 = y0 + 1, x1 = x0 + 1;
      const float vy0 = (y0 >= 0 && y0 < Hh) ? 1.f : 0.f;
      const float vy1 = (y1 >= 0 && y1 < Hh) ? 1.f : 0.f;
      const float vx0 = (x0 >= 0 && x0 < Ww) ? 1.f : 0.f;
      const float vx1 = (x1 >= 0 && x1 < Ww) ? 1.f : 0.f;
      const float w00 = (1.f - fy) * (1.f - fx) * vy0 * vx0 * m;
      const float w01 = (1.f - fy) * fx * vy0 * vx1 * m;
      const float w10 = fy * (1.f - fx) * vy1 * vx0 * m;
      const float w11 = fy * fx * vy1 * vx1 * m;
      const float* wk = &wg[k * 64];
      const int ly = y0 - ty0 + 2, lxw = x0 - tx0 + 2;
      if ((unsigned)ly < 11u && (unsigned)lxw < 19u) {
        const u16* base = &s_x[ly * 20 + lxw][gl * 8];
        const bf16x8 c00 = *(const bf16x8*)base;
        const bf16x8 c01 = *(const bf16x8*)(base + 40);
        const bf16x8 c10 = *(const bf16x8*)(base + 800);
        const bf16x8 c11 = *(const bf16x8*)(base + 840);
#pragma unroll
        for (int c = 0; c < 8; ++c) {
          const float s = w00 * (float)c00[c] + w01 * (float)c01[c]
                        + w10 * (float)c10[c] + w11 * (float)c11[c];
          const float4 wv0 = *(const float4*)&wk[c * 8];
          const float4 wv1 = *(const float4*)&wk[c * 8 + 4];
          acc[0] = fmaf(s, wv0.x, acc[0]); acc[1] = fmaf(s, wv0.y, acc[1]);
          acc[2] = fmaf(s, wv0.z, acc[2]); acc[3] = fmaf(s, wv0.w, acc[3]);
          acc[4] = fmaf(s, wv1.x, acc[4]); acc[5] = fmaf(s, wv1.y, acc[5]);
          acc[6] = fmaf(s, wv1.z, acc[6]); acc[7] = fmaf(s, wv1.w, acc[7]);
        }
      } else {
        const int cy0 = min(max(y0, 0), Hh - 1), cy1 = min(max(y1, 0), Hh - 1);
        const int cx0 = min(max(x0, 0), Ww - 1), cx1 = min(max(x1, 0), Ww - 1);
        const int i00 = cy0 * Ww + cx0, i01 = cy0 * Ww + cx1;
        const int i10 = cy1 * Ww + cx0, i11 = cy1 * Ww + cx1;
#pragma unroll
        for (int c = 0; c < 8; ++c) {
          const float* pl = xg + (size_t)c * HW;
          const float s = w00 * pl[i00] + w01 * pl[i01] + w10 * pl[i10] + w11 * pl[i11];
          const float4 wv0 = *(const float4*)&wk[c * 8];
          const float4 wv1 = *(const float4*)&wk[c * 8 + 4];
          acc[0] = fmaf(s, wv0.x, acc[0]); acc[1] = fmaf(s, wv0.y, acc[1]);
          acc[2] = fmaf(s, wv0.z, acc[2]); acc[3] = fmaf(s, wv0.w, acc[3]);
          acc[4] = fmaf(s, wv1.x, acc[4]); acc[5] = fmaf(s, wv1.y, acc[5]);
          acc[6] = fmaf(s, wv1.z, acc[6]); acc[7] = fmaf(s, wv1.w, acc[7]);
        }
      }
    }
#pragma unroll
    for (int o = 0; o < 8; ++o) og[(size_t)o * HW] = act_f<ACT>(acc[o]);
  }
}

// ---------------------------------------------------------------------------
// Bilinear 2x upsample (unchanged)
// ---------------------------------------------------------------------------
__global__ void k_up2(const float* __restrict__ in, float* __restrict__ out,
                      int planes, int h, int w)
{
  const int ow = 2 * w, oh = 2 * h;
  const int total = planes * oh * ow;
  int idx = blockIdx.x * TPB + threadIdx.x;
  if (idx >= total) return;
  const int pl = idx / (oh * ow);
  const int rem = idx - pl * (oh * ow);
  const int oyj = rem / ow, oxj = rem - oyj * ow;
  int iy0, iy1, ix0, ix1; float wy0, wy1, wx0, wx1;
  if (oyj & 1) { iy0 = oyj >> 1; iy1 = min(iy0 + 1, h - 1); wy0 = 0.75f; wy1 = 0.25f; }
  else         { iy1 = oyj >> 1; iy0 = max(iy1 - 1, 0);     wy0 = 0.25f; wy1 = 0.75f; }
  if (oxj & 1) { ix0 = oxj >> 1; ix1 = min(ix0 + 1, w - 1); wx0 = 0.75f; wx1 = 0.25f; }
  else         { ix1 = oxj >> 1; ix0 = max(ix1 - 1, 0);     wx0 = 0.25f; wx1 = 0.75f; }
  const float* pp = in + (size_t)pl * h * w;
  out[idx] = wy0 * (wx0 * pp[iy0 * w + ix0] + wx1 * pp[iy0 * w + ix1])
           + wy1 * (wx0 * pp[iy1 * w + ix0] + wx1 * pp[iy1 * w + ix1]);
}

// ---------------------------------------------------------------------------
// host-side helpers (B = 2 fixed)
// ---------------------------------------------------------------------------
static void conv3(hipStream_t st, const float* in1, int c1, const float* in2, int c2,
                  const u16* wbuf, const float* b, float* out, int Cout, int h, int wd, int act)
{
  int cocols = (Cout + 63) / 64, Coutpad = cocols * 64;
  dim3 grid((h / 16) * (wd / 16), cocols, 2);
  if (act == 0)      k_conv_mfma<0><<<grid, TPB, 0, st>>>(in1, c1, in2, c2, wbuf, b, out, Cout, Coutpad, h, wd);
  else if (act == 1) k_conv_mfma<1><<<grid, TPB, 0, st>>>(in1, c1, in2, c2, wbuf, b, out, Cout, Coutpad, h, wd);
  else               k_conv_mfma<2><<<grid, TPB, 0, st>>>(in1, c1, in2, c2, wbuf, b, out, Cout, Coutpad, h, wd);
}

static void dconv(hipStream_t st, const float* x, const float* om, const float* mask,
                  int maskC, int maskBase, const float* w, const float* b, float* out,
                  int h, int wd, int sigm, int act)
{
  dim3 grid((h / 8) * (wd / 16), 2, 2);
  if (sigm) {
    if (act) k_dconv5<1,1><<<grid, TPB, 0, st>>>(x, om, mask, maskC, maskBase, w, b, out, h, wd);
    else     k_dconv5<1,0><<<grid, TPB, 0, st>>>(x, om, mask, maskC, maskBase, w, b, out, h, wd);
  } else     k_dconv5<0,0><<<grid, TPB, 0, st>>>(x, om, mask, maskC, maskBase, w, b, out, h, wd);
}

static void up2(hipStream_t st, const float* in, float* out, int h, int w)
{
  int total = 128 * 4 * h * w;
  k_up2<<<(total + TPB - 1) / TPB, TPB, 0, st>>>(in, out, 128, h, w);
}

extern "C" void kernel_launch(void* const* d_in, const int* in_sizes, int n_in,
                              void* d_out, int out_size, void* d_ws, size_t ws_size,
                              hipStream_t stream)
{
  const float* const* in = (const float* const*)d_in;
  const float* nrf0 = in[0]; const float* rf0 = in[1]; const float* swf0 = in[2];
  const float* nrf1 = in[3]; const float* rf1 = in[4]; const float* swf1 = in[5];
  const float* nrf2 = in[6]; const float* rf2 = in[7]; const float* swf2 = in[8];

  float* ws = (float*)d_ws;
  const size_t L0 = (size_t)2 * 64 * 192 * 192;    // 4,718,592 floats
  float* A   = ws;
  float* Bb  = A   + L0;
  float* U   = Bb  + L0;
  float* OM  = U   + L0;                           // 2*216*192*192
  float* EM  = OM  + (size_t)2 * 216 * 192 * 192;  // 2*72*192*192
  float* of1 = EM  + (size_t)2 * 72 * 192 * 192;
  float* dn1 = of1 + L0 / 4;
  float* of2 = dn1 + L0 / 4;
  float* dn2 = of2 + L0 / 16;
  u16*   wp  = (u16*)(dn2 + L0 / 16);              // bf16 weight buffers

  float* dout = (float*)d_out;
  float* out0 = dout;
  float* sh0  = dout + L0;
  float* sh1  = sh0  + L0;
  float* sh2  = sh1  + L0 / 4;

  // ---- single-launch weight prep for all 22 convs (single bf16 plane) ----
  struct { int arg, cin, cout; } plist[22] = {
    {9,128,64},{11,64,64},{13,64,216},{15,128,64},{17,64,72},
    {21,128,64},{23,64,64},{25,64,216},{27,128,64},{29,64,72},
    {33,128,64},{35,64,64},{37,64,216},{39,128,64},{41,64,72},
    {45,128,64},{47,128,64},{49,128,64},{51,128,64},
    {53,128,64},{55,64,64},{57,64,216}};
  WPrepArgs wa;
  u16* wptr[22];
  int maxtot = 0;
  for (int i = 0; i < 22; ++i) {
    int cin = plist[i].cin, cout = plist[i].cout;
    int cpad = ((cout + 63) / 64) * 64;
    int tot = (cin / 32) * 9 * cpad * 40;
    wa.src[i] = in[plist[i].arg]; wa.dst[i] = wp;
    wa.cin[i] = cin; wa.cout[i] = cout; wa.coutpad[i] = cpad; wa.total[i] = tot;
    wptr[i] = wp; wp += tot;
    if (tot > maxtot) maxtot = tot;
  }
  k_wprep_all<<<dim3((maxtot + TPB - 1) / TPB, 22), TPB, 0, stream>>>(wa);

  u16* w_ocf0 = wptr[0];  u16* w_ocl0 = wptr[1];  u16* w_com0 = wptr[2];
  u16* w_em10 = wptr[3];  u16* w_em20 = wptr[4];
  u16* w_ocf1 = wptr[5];  u16* w_ocl1 = wptr[6];  u16* w_com1 = wptr[7];
  u16* w_em11 = wptr[8];  u16* w_em21 = wptr[9];
  u16* w_ocf2 = wptr[10]; u16* w_ocl2 = wptr[11]; u16* w_com2 = wptr[12];
  u16* w_em12 = wptr[13]; u16* w_em22 = wptr[14];
  u16* w_occ0 = wptr[15]; u16* w_fcc0 = wptr[16];
  u16* w_occ1 = wptr[17]; u16* w_fcc1 = wptr[18];
  u16* w_cas1 = wptr[19]; u16* w_cas2 = wptr[20]; u16* w_casc = wptr[21];

  // ----- level 2 (48x48) -----
  const int h2 = 48;
  conv3(stream, nrf2, 64, rf2, 64,  w_ocf2, in[34], A,   64,  h2, h2, 1);
  conv3(stream, A,    64, 0,   0,   w_ocl2, in[36], of2, 64,  h2, h2, 1);
  conv3(stream, swf2, 64, 0,   0,   w_com2, in[38], OM,  216, h2, h2, 0);
  conv3(stream, of2,  64, swf2, 64, w_em12, in[40], Bb,  64,  h2, h2, 1);
  conv3(stream, Bb,   64, 0,   0,   w_em22, in[42], EM,  72,  h2, h2, 2);
  dconv(stream, of2,  OM, EM,  72, 0,   in[43], in[44], sh2, h2, h2, 0, 0);
  dconv(stream, nrf2, OM, OM, 216, 144, in[43], in[44], dn2, h2, h2, 1, 1);

  // ----- level 1 (96x96) -----
  const int h1 = 96;
  up2(stream, of2, U, h2, h2);
  conv3(stream, nrf1, 64, rf1, 64,  w_ocf1, in[22], A,   64,  h1, h1, 1);
  conv3(stream, A,    64, U,   64,  w_occ1, in[50], Bb,  64,  h1, h1, 1);
  conv3(stream, Bb,   64, 0,   0,   w_ocl1, in[24], of1, 64,  h1, h1, 1);
  conv3(stream, swf1, 64, 0,   0,   w_com1, in[26], OM,  216, h1, h1, 0);
  conv3(stream, of1,  64, swf1, 64, w_em11, in[28], A,   64,  h1, h1, 1);
  conv3(stream, A,    64, 0,   0,   w_em21, in[30], EM,  72,  h1, h1, 2);
  dconv(stream, of1,  OM, EM,  72, 0,   in[31], in[32], sh1, h1, h1, 0, 0);
  dconv(stream, nrf1, OM, OM, 216, 144, in[31], in[32], A,   h1, h1, 1, 0);
  up2(stream, dn2, U, h2, h2);
  conv3(stream, A,    64, U,   64,  w_fcc1, in[52], dn1, 64,  h1, h1, 1);

  // ----- level 0 (192x192) -----
  const int h0 = 192;
  up2(stream, of1, U, h1, h1);
  conv3(stream, nrf0, 64, rf0, 64,  w_ocf0, in[10], A,   64,  h0, h0, 1);
  conv3(stream, A,    64, U,   64,  w_occ0, in[46], Bb,  64,  h0, h0, 1);
  conv3(stream, Bb,   64, 0,   0,   w_ocl0, in[12], A,   64,  h0, h0, 1);
  conv3(stream, swf0, 64, 0,   0,   w_com0, in[14], OM,  216, h0, h0, 0);
  conv3(stream, A,    64, swf0, 64, w_em10, in[16], Bb,  64,  h0, h0, 1);
  conv3(stream, Bb,   64, 0,   0,   w_em20, in[18], EM,  72,  h0, h0, 2);
  dconv(stream, A,    OM, EM,  72, 0,   in[19], in[20], sh0, h0, h0, 0, 0);
  dconv(stream, nrf0, OM, OM, 216, 144, in[19], in[20], Bb,  h0, h0, 1, 0);
  up2(stream, dn1, U, h1, h1);
  conv3(stream, Bb,   64, U,   64,  w_fcc0, in[48], A,   64,  h0, h0, 0);
  conv3(stream, A,    64, rf0, 64,  w_cas1, in[54], Bb,  64,  h0, h0, 1);
  conv3(stream, Bb,   64, 0,   0,   w_cas2, in[56], U,   64,  h0, h0, 1);
  conv3(stream, U,    64, 0,   0,   w_casc, in[58], OM,  216, h0, h0, 0);
  dconv(stream, A,    OM, OM, 216, 144, in[59], in[60], out0, h0, h0, 1, 1);
}